// Round 3
// baseline (179.294 us; speedup 1.0000x reference)
//
#include <hip/hip_runtime.h>
#include <math.h>

#define HOP       128
#define NFFT      512
#define NBINS     257
#define NFRAMES   4000
#define NB        16
#define OUT_LEN   512383          // (4000-1)*128 + 512 - 1
#define CPR       8               // chunks per range (per wave)
#define RPB       501             // ranges per batch = ceil(4003/8)
#define NCHUNK    4003            // output chunks of 128 (last is 127)
#define SP        72              // stage-1/2 P layout row stride (float2); 144 floats == 16 mod 32
#define SQB       72              // stage-2/3 Q layout m0 stride (float2)
#define SQN       9               // stage-2/3 Q layout n0 stride (odd -> bank permutation)
#define PBUF      576             // per-wave scratch size (float2)

// Inverse (e^{+i}) 8-point DFT, DIF with output bit-reversal folded in.
__device__ __forceinline__ void dft8_inv(const float* xr, const float* xi,
                                         float* yr, float* yi)
{
    const float C = 0.70710678118654752f;
    float ar[8], ai[8];
    ar[0]=xr[0]+xr[4]; ai[0]=xi[0]+xi[4];
    ar[1]=xr[1]+xr[5]; ai[1]=xi[1]+xi[5];
    ar[2]=xr[2]+xr[6]; ai[2]=xi[2]+xi[6];
    ar[3]=xr[3]+xr[7]; ai[3]=xi[3]+xi[7];
    float t0r=xr[0]-xr[4], t0i=xi[0]-xi[4];
    float t1r=xr[1]-xr[5], t1i=xi[1]-xi[5];
    float t2r=xr[2]-xr[6], t2i=xi[2]-xi[6];
    float t3r=xr[3]-xr[7], t3i=xi[3]-xi[7];
    ar[4]= t0r;            ai[4]= t0i;             // *W8^0
    ar[5]= C*(t1r-t1i);    ai[5]= C*(t1r+t1i);     // *W8^1 = C(1+i)
    ar[6]=-t2i;            ai[6]= t2r;             // *W8^2 = i
    ar[7]=-C*(t3r+t3i);    ai[7]= C*(t3r-t3i);     // *W8^3 = C(-1+i)
    float br[8], bi[8];
    br[0]=ar[0]+ar[2]; bi[0]=ai[0]+ai[2];
    br[1]=ar[1]+ar[3]; bi[1]=ai[1]+ai[3];
    br[2]=ar[0]-ar[2]; bi[2]=ai[0]-ai[2];
    { float u=ar[1]-ar[3], v=ai[1]-ai[3]; br[3]=-v; bi[3]=u; }   // *i
    br[4]=ar[4]+ar[6]; bi[4]=ai[4]+ai[6];
    br[5]=ar[5]+ar[7]; bi[5]=ai[5]+ai[7];
    br[6]=ar[4]-ar[6]; bi[6]=ai[4]-ai[6];
    { float u=ar[5]-ar[7], v=ai[5]-ai[7]; br[7]=-v; bi[7]=u; }   // *i
    // final radix-2 + bitrev3 output placement
    yr[0]=br[0]+br[1]; yi[0]=bi[0]+bi[1];
    yr[4]=br[0]-br[1]; yi[4]=bi[0]-bi[1];
    yr[2]=br[2]+br[3]; yi[2]=bi[2]+bi[3];
    yr[6]=br[2]-br[3]; yi[6]=bi[2]-bi[3];
    yr[1]=br[4]+br[5]; yi[1]=bi[4]+bi[5];
    yr[5]=br[4]-br[5]; yi[5]=bi[4]-bi[5];
    yr[3]=br[6]+br[7]; yi[3]=bi[6]+bi[7];
    yr[7]=br[6]-br[7]; yi[7]=bi[6]-bi[7];
}

// One wave per chunk-range: 8 output chunks + 3 halo frames, radix-8
// 512-pt inverse FFT (3 stages, 2 LDS round-trips), register shift-
// accumulator overlap-add, coalesced exactly-once stores. No atomics,
// no block-level syncs. Conflict-free padded LDS layouts.
__global__ __launch_bounds__(256)
void istft_r8_kernel(const float* __restrict__ re,
                     const float* __restrict__ im,
                     float* __restrict__ out)
{
    __shared__ float2 pbuf[4][PBUF];   // 4 waves * 4608 B = 18432 B -> 8 blocks/CU

    const int tid = threadIdx.x;
    const int wv  = tid >> 6;
    const int l   = tid & 63;

    float2* P = pbuf[wv];

    const int rid = blockIdx.x * 4 + wv;     // 0..8015, exact
    const int b   = rid / RPB;
    const int rr  = rid - b * RPB;
    const int c0  = rr * CPR;
    const int fend = min(c0 + CPR - 1, NCHUNK - 1);

    const float* __restrict__ reb = re + (size_t)b * NFRAMES * NBINS;
    const float* __restrict__ imb = im + (size_t)b * NFRAMES * NBINS;
    float* __restrict__ outb = out + (size_t)b * OUT_LEN;

    // Frame-invariant twiddles.
    // Stage 1: e^{+i 2pi n0 l / 512}, n0 = 0..7
    float s1r[8], s1i[8];
    {
        float sr, cr;
        __sincosf(6.2831853071795864f * (float)l * (1.0f/512.0f), &sr, &cr);
        s1r[0] = 1.0f; s1i[0] = 0.0f; s1r[1] = cr; s1i[1] = sr;
        #pragma unroll
        for (int k = 2; k < 8; ++k) {
            s1r[k] = s1r[k-1]*cr - s1i[k-1]*sr;
            s1i[k] = s1r[k-1]*sr + s1i[k-1]*cr;
        }
    }
    // Stage 2: e^{+i 2pi m0 (l&7) / 64}, m0 = 0..7
    float s2r[8], s2i[8];
    {
        float sr, cr;
        __sincosf(6.2831853071795864f * (float)(l & 7) * (1.0f/64.0f), &sr, &cr);
        s2r[0] = 1.0f; s2i[0] = 0.0f; s2r[1] = cr; s2i[1] = sr;
        #pragma unroll
        for (int k = 2; k < 8; ++k) {
            s2r[k] = s2r[k-1]*cr - s2i[k-1]*sr;
            s2i[k] = s2r[k-1]*sr + s2i[k-1]*cr;
        }
    }

    // Lane's inverse-window weights (output n = l + 64*m1).
    // OLA denominator of 4x-overlapped squared periodic Hann is exactly 1.5,
    // so invwin[n] = hann(n) / (512 * 1.5) = (0.5 - 0.5 cos(2 pi n/512)) / 768.
    // cos(theta + m1*pi/4) via rotation recurrence.
    float ww[8];
    {
        float sn, cs;
        __sincosf(6.2831853071795864f * (float)l * (1.0f/512.0f), &sn, &cs);
        const float R = 0.70710678118654752f;   // cos(pi/4) = sin(pi/4)
        float c = cs, s = sn;
        #pragma unroll
        for (int m1 = 0; m1 < 8; ++m1) {
            ww[m1] = (0.5f - 0.5f * c) * (1.0f/768.0f);
            const float cn = (c - s) * R;
            const float sn2 = (s + c) * R;
            c = cn; s = sn2;
        }
    }

    float acc[8];
    #pragma unroll
    for (int r = 0; r < 8; ++r) acc[r] = 0.0f;

    const int n0s = l >> 3, gs = l & 7;   // stage-2 lane assignment
    const int m0t = l >> 3, n0t = l & 7;  // stage-3 lane assignment

    for (int f = c0 - 3; f <= fend; ++f) {
        if (f >= 0 && f < NFRAMES) {
            const float* __restrict__ rb = reb + (size_t)f * NBINS;
            const float* __restrict__ ib = imb + (size_t)f * NBINS;

            // Load x[64a + l], Hermitian-extended. a<4 is always direct.
            float xr[8], xi[8];
            #pragma unroll
            for (int a = 0; a < 4; ++a) {
                xr[a] = rb[64*a + l];
                xi[a] = ib[64*a + l];
            }
            #pragma unroll
            for (int a = 4; a < 8; ++a) {
                const int t  = 64*a + l;
                const int tt = (t <= 256) ? t : (512 - t);
                const float sg = (t <= 256) ? 1.0f : -1.0f;
                xr[a] = rb[tt];
                xi[a] = sg * ib[tt];
            }

            // Stage 1: DFT8 over a -> p[n0]; twiddle W512^{n0 l}; store.
            float pr[8], pi[8];
            dft8_inv(xr, xi, pr, pi);
            #pragma unroll
            for (int n0 = 0; n0 < 8; ++n0) {
                const float tr = pr[n0]*s1r[n0] - pi[n0]*s1i[n0];
                const float ti = pr[n0]*s1i[n0] + pi[n0]*s1r[n0];
                P[SP*n0 + l] = make_float2(tr, ti);
            }
            __builtin_amdgcn_wave_barrier();

            // Stage 2: gather p[n0s][8e+gs], DFT8 over e, twiddle W64^{m0 gs}, store.
            #pragma unroll
            for (int e = 0; e < 8; ++e) {
                const float2 v = P[SP*n0s + 8*e + gs];
                xr[e] = v.x; xi[e] = v.y;
            }
            __builtin_amdgcn_wave_barrier();
            float qr[8], qi[8];
            dft8_inv(xr, xi, qr, qi);
            #pragma unroll
            for (int m0 = 0; m0 < 8; ++m0) {
                const float tr = qr[m0]*s2r[m0] - qi[m0]*s2i[m0];
                const float ti = qr[m0]*s2i[m0] + qi[m0]*s2r[m0];
                P[SQB*m0 + SQN*n0s + gs] = make_float2(tr, ti);
            }
            __builtin_amdgcn_wave_barrier();

            // Stage 3: gather q[m0t][n0t][g], DFT8 over g -> X[l + 64*m1].
            #pragma unroll
            for (int g = 0; g < 8; ++g) {
                const float2 v = P[SQB*m0t + SQN*n0t + g];
                xr[g] = v.x; xi[g] = v.y;
            }
            __builtin_amdgcn_wave_barrier();
            float yr[8], yi[8];
            dft8_inv(xr, xi, yr, yi);

            // Window + accumulate (real part only).
            #pragma unroll
            for (int m1 = 0; m1 < 8; ++m1) acc[m1] += yr[m1] * ww[m1];
        }

        // Emit chunk f (positions f*128 + {0..127}) — complete after adding frame f.
        if (f >= c0) {
            const int pos0 = f * HOP + l;        // max 512319 < OUT_LEN, always valid
            const int pos1 = pos0 + 64;          // max 512383 == OUT_LEN at the very end
            outb[pos0] = acc[0];
            if (pos1 < OUT_LEN) outb[pos1] = acc[1];
        }

        // Shift the accumulator window forward by 128 samples (2 slots).
        #pragma unroll
        for (int r = 0; r < 6; ++r) acc[r] = acc[r + 2];
        acc[6] = 0.0f; acc[7] = 0.0f;
    }
}

extern "C" void kernel_launch(void* const* d_in, const int* in_sizes, int n_in,
                              void* d_out, int out_size, void* d_ws, size_t ws_size,
                              hipStream_t stream) {
    (void)in_sizes; (void)n_in; (void)d_ws; (void)ws_size; (void)out_size;
    const float* re = (const float*)d_in[0];
    const float* im = (const float*)d_in[1];
    float* out = (float*)d_out;

    // 16 batches x 501 ranges = 8016 waves; 4 waves per 256-thread block.
    const int nblocks = (NB * RPB) / 4;   // 2004
    istft_r8_kernel<<<dim3(nblocks), dim3(256), 0, stream>>>(re, im, out);
}

// Round 4
// 175.794 us; speedup vs baseline: 1.0199x; 1.0199x over previous
//
#include <hip/hip_runtime.h>
#include <math.h>

#define HOP       128
#define NBINS     257
#define NFRAMES   4000
#define NB        16
#define OUT_LEN   512383          // (4000-1)*128 + 512 - 1
#define CPR       8               // chunks per range (per wave)
#define RPB       501             // ranges per batch = ceil(4003/8)
#define NCHUNK    4003            // output chunks of 128 (last has 127 samples)
#define PB        320             // per-wave LDS scratch (float2), reused by 3 transposes

__device__ __forceinline__ float2 cmul(float2 a, float2 b) {
    return make_float2(a.x*b.x - a.y*b.y, a.x*b.y + a.y*b.x);
}

// Inverse-sign DFT4: y[t] = sum_j x[j] * i^(j*t)
__device__ __forceinline__ void dft4(const float2* x, float2* y) {
    const float s0r=x[0].x+x[2].x, s0i=x[0].y+x[2].y;
    const float d0r=x[0].x-x[2].x, d0i=x[0].y-x[2].y;
    const float s1r=x[1].x+x[3].x, s1i=x[1].y+x[3].y;
    const float d1r=x[1].x-x[3].x, d1i=x[1].y-x[3].y;
    y[0]=make_float2(s0r+s1r, s0i+s1i);
    y[2]=make_float2(s0r-s1r, s0i-s1i);
    y[1]=make_float2(d0r-d1i, d0i+d1r);   // d0 + i*d1
    y[3]=make_float2(d0r+d1i, d0i-d1r);   // d0 - i*d1
}

// Real-packed iSTFT: per frame, build 256-pt packed spectrum C[k] from the
// 257 Hermitian bins, run a 256-pt complex inverse FFT (4 stages of in-lane
// DFT4, 3 conflict-free LDS transposes), unpack even/odd real samples,
// window, and overlap-add in a register shift-accumulator. One wave per
// 8-chunk output range (+3 halo frames). No atomics, no block syncs.
__global__ __launch_bounds__(256)
void istft_pk_kernel(const float* __restrict__ re,
                     const float* __restrict__ im,
                     float* __restrict__ out)
{
    __shared__ float2 pbuf[4][PB];    // 4 waves * 2560 B = 10240 B / block

    const int tid = threadIdx.x;
    const int wv  = tid >> 6;
    const int l   = tid & 63;
    float2* P = pbuf[wv];

    const int rid = blockIdx.x * 4 + wv;     // 0..8015 exact
    const int b   = rid / RPB;
    const int rr  = rid - b * RPB;
    const int c0  = rr * CPR;
    const int fend = min(c0 + CPR - 1, NCHUNK - 1);

    const float* __restrict__ reb = re + (size_t)b * NFRAMES * NBINS;
    const float* __restrict__ imb = im + (size_t)b * NFRAMES * NBINS;
    float* __restrict__ outb = out + (size_t)b * OUT_LEN;

    // ---- frame-invariant per-lane constants ----
    const float TWO_PI = 6.2831853071795864f;
    // Pack twiddle: e^{2 pi i (l+64j)/512}; step j -> rotate by pi/4.
    float2 ctw[4];
    {
        float s, c; __sincosf(TWO_PI * (float)l * (1.0f/512.0f), &s, &c);
        const float R = 0.70710678118654752f;
        ctw[0] = make_float2(c, s);
        #pragma unroll
        for (int j = 1; j < 4; ++j) {
            const float cn = (c - s) * R, sn = (s + c) * R;
            c = cn; s = sn; ctw[j] = make_float2(c, s);
        }
    }
    // Stage-1 twiddle: w^t0, w = e^{2 pi i l/256}
    float2 w1, w2, w3;
    { float s, c; __sincosf(TWO_PI * (float)l * (1.0f/256.0f), &s, &c);
      w1 = make_float2(c, s); w2 = cmul(w1, w1); w3 = cmul(w2, w1); }
    // Stage-2 twiddle: e^{2 pi i (l&15) t1/64}
    float2 b1, b2, b3;
    { float s, c; __sincosf(TWO_PI * (float)(l & 15) * (1.0f/64.0f), &s, &c);
      b1 = make_float2(c, s); b2 = cmul(b1, b1); b3 = cmul(b2, b1); }
    // Stage-3 twiddle: e^{2 pi i (l&3) t2/16}
    float2 q1, q2, q3;
    { float s, c; __sincosf(TWO_PI * (float)(l & 3) * (1.0f/16.0f), &s, &c);
      q1 = make_float2(c, s); q2 = cmul(q1, q1); q3 = cmul(q2, q1); }
    // Window weights for samples 2l+128o (x) and 2l+1+128o (y), o=0..3.
    // invwin(s) = (0.5 - 0.5 cos(2 pi s/512)) / (512 * 1.5); scale = 0.5/768.
    float wwx[4], wwy[4];
    {
        const float S = 6.5104166667e-4f;   // 0.5/768
        float sx, cx; __sincosf(TWO_PI * (float)(2*l) * (1.0f/512.0f), &sx, &cx);
        wwx[0]=S*(1.0f-cx); wwx[1]=S*(1.0f+sx); wwx[2]=S*(1.0f+cx); wwx[3]=S*(1.0f-sx);
        float sy, cy; __sincosf(TWO_PI * (float)(2*l+1) * (1.0f/512.0f), &sy, &cy);
        wwy[0]=S*(1.0f-cy); wwy[1]=S*(1.0f+sy); wwy[2]=S*(1.0f+cy); wwy[3]=S*(1.0f-sy);
    }
    // Conflict-free transpose layouts (float2 index; each bank-pair hit 4x/wave).
    const int a1w = l;                                        // + 64*t0
    const int a1r = (l & 15) + 64 * (l >> 4);                 // + 16*q
    const int a2w = (l & 15) + 20 * (l >> 4);                 // + 80*t1
    const int a2r = (l & 3) + 20 * ((l >> 2) & 3) + 80 * (l >> 4);   // + 4*r
    const int a3w = ((l >> 2) & 3) + 4 * (l >> 4) + 20 * (l & 3);    // + 80*t2
    const int a3r = (l & 3) + 4 * ((l >> 2) & 3) + 80 * (l >> 4);    // + 20*k0

    float accx[4], accy[4];
    #pragma unroll
    for (int o = 0; o < 4; ++o) { accx[o] = 0.0f; accy[o] = 0.0f; }

    for (int f = c0 - 3; f <= fend; ++f) {
        if (f >= 0 && f < NFRAMES) {
            const float* __restrict__ rb = reb + (size_t)f * NBINS;
            const float* __restrict__ ib = imb + (size_t)f * NBINS;

            // Build packed spectrum C[l+64j] (unnormalized x2):
            // C[k] = (Y[k]+conj(Y[256-k])) + i e^{2pi i k/512} (Y[k]-conj(Y[256-k]))
            float2 Cv[4];
            #pragma unroll
            for (int j = 0; j < 4; ++j) {
                const int k  = l + 64*j;
                const int km = 256 - k;
                float ydr = rb[k],  ydi = ib[k];
                float ymr = rb[km], ymi = ib[km];
                if (j == 0) {                       // k==0: Im of DC & Nyquist ignored
                    const bool z = (l == 0);
                    ydi = z ? 0.0f : ydi;
                    ymi = z ? 0.0f : ymi;
                }
                const float er  = ydr + ymr, ei  = ydi - ymi;
                const float fr2 = ydr - ymr, fi2 = ydi + ymi;
                const float gr = ctw[j].x*fr2 - ctw[j].y*fi2;
                const float gi = ctw[j].x*fi2 + ctw[j].y*fr2;
                Cv[j] = make_float2(er - gi, ei + gr);
            }

            float2 A[4], G[4];
            // Stage 1: DFT4 over j (stride 64), twiddle w^{l t0}.
            dft4(Cv, A);
            A[1] = cmul(A[1], w1); A[2] = cmul(A[2], w2); A[3] = cmul(A[3], w3);
            P[a1w] = A[0]; P[a1w+64] = A[1]; P[a1w+128] = A[2]; P[a1w+192] = A[3];
            __builtin_amdgcn_wave_barrier();
            G[0] = P[a1r]; G[1] = P[a1r+16]; G[2] = P[a1r+32]; G[3] = P[a1r+48];
            __builtin_amdgcn_wave_barrier();

            // Stage 2: DFT4 over q (stride 16), twiddle e^{2pi i (l&15) t1/64}.
            dft4(G, A);
            A[1] = cmul(A[1], b1); A[2] = cmul(A[2], b2); A[3] = cmul(A[3], b3);
            P[a2w] = A[0]; P[a2w+80] = A[1]; P[a2w+160] = A[2]; P[a2w+240] = A[3];
            __builtin_amdgcn_wave_barrier();
            G[0] = P[a2r]; G[1] = P[a2r+4]; G[2] = P[a2r+8]; G[3] = P[a2r+12];
            __builtin_amdgcn_wave_barrier();

            // Stage 3: DFT4 over r (stride 4), twiddle e^{2pi i (l&3) t2/16}.
            dft4(G, A);
            A[1] = cmul(A[1], q1); A[2] = cmul(A[2], q2); A[3] = cmul(A[3], q3);
            P[a3w] = A[0]; P[a3w+80] = A[1]; P[a3w+160] = A[2]; P[a3w+240] = A[3];
            __builtin_amdgcn_wave_barrier();
            G[0] = P[a3r]; G[1] = P[a3r+20]; G[2] = P[a3r+40]; G[3] = P[a3r+60];
            __builtin_amdgcn_wave_barrier();

            // Stage 4: final DFT4 -> lane l holds c[l + 64*o], o=0..3.
            dft4(G, A);

            // Unpack: x[2n]=Re, x[2n+1]=Im; window + accumulate.
            #pragma unroll
            for (int o = 0; o < 4; ++o) {
                accx[o] += A[o].x * wwx[o];
                accy[o] += A[o].y * wwy[o];
            }
        }

        // Emit chunk f: real samples 128f + 2l (+1). Complete after frame f.
        if (f >= c0) {
            const int s0 = f * HOP + 2*l;       // max 512382 < OUT_LEN, always valid
            outb[s0] = accx[0];
            const int s1 = s0 + 1;              // == OUT_LEN only at f=4002, l=63
            if (s1 < OUT_LEN) outb[s1] = accy[0];
        }

        // Shift accumulator forward one chunk (128 samples).
        #pragma unroll
        for (int o = 0; o < 3; ++o) { accx[o] = accx[o+1]; accy[o] = accy[o+1]; }
        accx[3] = 0.0f; accy[3] = 0.0f;
    }
}

extern "C" void kernel_launch(void* const* d_in, const int* in_sizes, int n_in,
                              void* d_out, int out_size, void* d_ws, size_t ws_size,
                              hipStream_t stream) {
    (void)in_sizes; (void)n_in; (void)d_ws; (void)ws_size; (void)out_size;
    const float* re = (const float*)d_in[0];
    const float* im = (const float*)d_in[1];
    float* out = (float*)d_out;

    // 16 batches x 501 ranges = 8016 waves; 4 waves per 256-thread block.
    const int nblocks = (NB * RPB) / 4;   // 2004
    istft_pk_kernel<<<dim3(nblocks), dim3(256), 0, stream>>>(re, im, out);
}

// Round 5
// 174.892 us; speedup vs baseline: 1.0252x; 1.0052x over previous
//
#include <hip/hip_runtime.h>
#include <math.h>

#define HOP       128
#define NBINS     257
#define NFRAMES   4000
#define NB        16
#define OUT_LEN   512383          // (4000-1)*128 + 512 - 1
#define CPR       8               // chunks per range (per wave)
#define RPB       501             // ranges per batch = ceil(4003/8)
#define NCHUNK    4003            // output chunks of 128 (last has 127 samples)
#define PBF       320             // per-wave LDS scratch (float2) per buffer

__device__ __forceinline__ float2 cmul(float2 a, float2 b) {
    return make_float2(a.x*b.x - a.y*b.y, a.x*b.y + a.y*b.x);
}

// Inverse-sign DFT4: y[t] = sum_j x[j] * i^(j*t)
__device__ __forceinline__ void dft4(const float2* x, float2* y) {
    const float s0r=x[0].x+x[2].x, s0i=x[0].y+x[2].y;
    const float d0r=x[0].x-x[2].x, d0i=x[0].y-x[2].y;
    const float s1r=x[1].x+x[3].x, s1i=x[1].y+x[3].y;
    const float d1r=x[1].x-x[3].x, d1i=x[1].y-x[3].y;
    y[0]=make_float2(s0r+s1r, s0i+s1i);
    y[2]=make_float2(s0r-s1r, s0i-s1i);
    y[1]=make_float2(d0r-d1i, d0i+d1r);   // d0 + i*d1
    y[3]=make_float2(d0r+d1i, d0i-d1r);   // d0 - i*d1
}

// Real-packed iSTFT, software-pipelined: packed 256-pt inverse FFT per frame
// (4 in-lane DFT4 stages, 3 LDS transposes), double-buffered LDS so frame
// f+1's global loads + stage1 overlap frame f's LDS round-trip stalls.
// One wave per 8-chunk range (+3 halo frames); register OLA; no atomics,
// no barriers of any kind.
__global__ __launch_bounds__(256)
void istft_pk2_kernel(const float* __restrict__ re,
                      const float* __restrict__ im,
                      float* __restrict__ out)
{
    __shared__ float2 bufA[4][PBF];   // 2 * 4 * 2560 B = 20480 B / block
    __shared__ float2 bufB[4][PBF];

    const int tid = threadIdx.x;
    const int wv  = tid >> 6;
    const int l   = tid & 63;
    float2* PA = bufA[wv];
    float2* PBp = bufB[wv];

    const int rid = blockIdx.x * 4 + wv;     // 0..8015 exact
    const int b   = rid / RPB;
    const int rr  = rid - b * RPB;
    const int c0  = rr * CPR;
    const int fend = min(c0 + CPR - 1, NCHUNK - 1);

    const float* __restrict__ reb = re + (size_t)b * NFRAMES * NBINS;
    const float* __restrict__ imb = im + (size_t)b * NFRAMES * NBINS;
    float* __restrict__ outb = out + (size_t)b * OUT_LEN;

    // ---- frame-invariant per-lane constants ----
    const float TWO_PI = 6.2831853071795864f;
    // Pack twiddle: e^{2 pi i (l+64j)/512}; step j -> rotate by pi/4.
    float2 ctw[4];
    {
        float s, c; __sincosf(TWO_PI * (float)l * (1.0f/512.0f), &s, &c);
        const float R = 0.70710678118654752f;
        ctw[0] = make_float2(c, s);
        #pragma unroll
        for (int j = 1; j < 4; ++j) {
            const float cn = (c - s) * R, sn = (s + c) * R;
            c = cn; s = sn; ctw[j] = make_float2(c, s);
        }
    }
    float2 w1, w2, w3;
    { float s, c; __sincosf(TWO_PI * (float)l * (1.0f/256.0f), &s, &c);
      w1 = make_float2(c, s); w2 = cmul(w1, w1); w3 = cmul(w2, w1); }
    float2 b1, b2, b3;
    { float s, c; __sincosf(TWO_PI * (float)(l & 15) * (1.0f/64.0f), &s, &c);
      b1 = make_float2(c, s); b2 = cmul(b1, b1); b3 = cmul(b2, b1); }
    float2 q1, q2, q3;
    { float s, c; __sincosf(TWO_PI * (float)(l & 3) * (1.0f/16.0f), &s, &c);
      q1 = make_float2(c, s); q2 = cmul(q1, q1); q3 = cmul(q2, q1); }
    // Window weights for samples 2l+128o (x) and 2l+1+128o (y), o=0..3.
    float wwx[4], wwy[4];
    {
        const float S = 6.5104166667e-4f;   // 0.5/768
        float sx, cx; __sincosf(TWO_PI * (float)(2*l) * (1.0f/512.0f), &sx, &cx);
        wwx[0]=S*(1.0f-cx); wwx[1]=S*(1.0f+sx); wwx[2]=S*(1.0f+cx); wwx[3]=S*(1.0f-sx);
        float sy, cy; __sincosf(TWO_PI * (float)(2*l+1) * (1.0f/512.0f), &sy, &cy);
        wwy[0]=S*(1.0f-cy); wwy[1]=S*(1.0f+sy); wwy[2]=S*(1.0f+cy); wwy[3]=S*(1.0f-sy);
    }
    // Conflict-free transpose layouts (float2 index; each bank-pair hit 4x/wave).
    const int a1w = l;                                        // + 64*t0
    const int a1r = (l & 15) + 64 * (l >> 4);                 // + 16*q
    const int a2w = (l & 15) + 20 * (l >> 4);                 // + 80*t1
    const int a2r = (l & 3) + 20 * ((l >> 2) & 3) + 80 * (l >> 4);   // + 4*r
    const int a3w = ((l >> 2) & 3) + 4 * (l >> 4) + 20 * (l & 3);    // + 80*t2
    const int a3r = (l & 3) + 4 * ((l >> 2) & 3) + 80 * (l >> 4);    // + 20*k0

    float accx[4], accy[4];
    #pragma unroll
    for (int o = 0; o < 4; ++o) { accx[o] = 0.0f; accy[o] = 0.0f; }

    // Raw prefetch registers for the next frame's inputs.
    float dr[4], di[4], mr4[4], mi4[4];

    auto issue_loads = [&](int fq) {
        const int fc = min(max(fq, 0), NFRAMES - 1);
        const float* __restrict__ rb = reb + (size_t)fc * NBINS;
        const float* __restrict__ ib = imb + (size_t)fc * NBINS;
        #pragma unroll
        for (int j = 0; j < 4; ++j) {
            const int k = l + 64*j, km = 256 - k;
            dr[j]  = rb[k];  di[j]  = ib[k];
            mr4[j] = rb[km]; mi4[j] = ib[km];
        }
    };

    auto stage1 = [&](float2* __restrict__ P) {
        // Pack C[k] = (Y[k]+conj(Y[256-k])) + i e^{2pi i k/512}(Y[k]-conj(Y[256-k]))
        float2 Cv[4];
        #pragma unroll
        for (int j = 0; j < 4; ++j) {
            float ydr = dr[j], ydi = di[j], ymr = mr4[j], ymi = mi4[j];
            if (j == 0) {                       // k==0: Im of DC & Nyquist ignored
                const bool z = (l == 0);
                ydi = z ? 0.0f : ydi;
                ymi = z ? 0.0f : ymi;
            }
            const float er  = ydr + ymr, ei  = ydi - ymi;
            const float fr2 = ydr - ymr, fi2 = ydi + ymi;
            const float gr = ctw[j].x*fr2 - ctw[j].y*fi2;
            const float gi = ctw[j].x*fi2 + ctw[j].y*fr2;
            Cv[j] = make_float2(er - gi, ei + gr);
        }
        float2 A[4];
        dft4(Cv, A);
        A[1] = cmul(A[1], w1); A[2] = cmul(A[2], w2); A[3] = cmul(A[3], w3);
        P[a1w] = A[0]; P[a1w+64] = A[1]; P[a1w+128] = A[2]; P[a1w+192] = A[3];
    };

    auto stages234 = [&](float2* __restrict__ P, int f) {
        float2 A[4], G[4];
        G[0] = P[a1r]; G[1] = P[a1r+16]; G[2] = P[a1r+32]; G[3] = P[a1r+48];
        dft4(G, A);
        A[1] = cmul(A[1], b1); A[2] = cmul(A[2], b2); A[3] = cmul(A[3], b3);
        P[a2w] = A[0]; P[a2w+80] = A[1]; P[a2w+160] = A[2]; P[a2w+240] = A[3];
        G[0] = P[a2r]; G[1] = P[a2r+4]; G[2] = P[a2r+8]; G[3] = P[a2r+12];
        dft4(G, A);
        A[1] = cmul(A[1], q1); A[2] = cmul(A[2], q2); A[3] = cmul(A[3], q3);
        P[a3w] = A[0]; P[a3w+80] = A[1]; P[a3w+160] = A[2]; P[a3w+240] = A[3];
        G[0] = P[a3r]; G[1] = P[a3r+20]; G[2] = P[a3r+40]; G[3] = P[a3r+60];
        dft4(G, A);
        if (f >= 0 && f < NFRAMES) {            // wave-uniform gate
            #pragma unroll
            for (int o = 0; o < 4; ++o) {
                accx[o] += A[o].x * wwx[o];
                accy[o] += A[o].y * wwy[o];
            }
        }
        if (f >= c0) {                          // emit chunk f (complete now)
            const int s0 = f * HOP + 2*l;       // max 512382 < OUT_LEN
            outb[s0] = accx[0];
            const int s1 = s0 + 1;              // == OUT_LEN only at the very end
            if (s1 < OUT_LEN) outb[s1] = accy[0];
        }
        #pragma unroll
        for (int o = 0; o < 3; ++o) { accx[o] = accx[o+1]; accy[o] = accy[o+1]; }
        accx[3] = 0.0f; accy[3] = 0.0f;
    };

    // ---- software-pipelined frame loop ----
    issue_loads(c0 - 3);
    stage1(PA);
    for (int f = c0 - 3; f <= fend; f += 2) {
        issue_loads(f + 1);      // in flight during stages234(f)
        stages234(PA, f);
        stage1(PBp);             // consumes f+1 loads
        if (f + 1 <= fend) {
            issue_loads(f + 2);
            stages234(PBp, f + 1);
            stage1(PA);
        }
    }
}

extern "C" void kernel_launch(void* const* d_in, const int* in_sizes, int n_in,
                              void* d_out, int out_size, void* d_ws, size_t ws_size,
                              hipStream_t stream) {
    (void)in_sizes; (void)n_in; (void)d_ws; (void)ws_size; (void)out_size;
    const float* re = (const float*)d_in[0];
    const float* im = (const float*)d_in[1];
    float* out = (float*)d_out;

    // 16 batches x 501 ranges = 8016 waves; 4 waves per 256-thread block.
    const int nblocks = (NB * RPB) / 4;   // 2004
    istft_pk2_kernel<<<dim3(nblocks), dim3(256), 0, stream>>>(re, im, out);
}